// Round 2
// baseline (73.977 us; speedup 1.0000x reference)
//
#include <hip/hip_runtime.h>
#include <hip/hip_bf16.h>

#define B_DIM  8
#define N_DIM  2048
#define CIN    256
#define COUT   256
#define F_DIM  8
#define EPS    1e-4f

using short8 = __attribute__((ext_vector_type(8))) short;
using f32x4  = __attribute__((ext_vector_type(4))) float;

__device__ __forceinline__ unsigned short f2bf(float f) {
    union { float f; unsigned u; } x; x.f = f;
    unsigned r = x.u + 0x7FFFu + ((x.u >> 16) & 1u);   // RNE
    return (unsigned short)(r >> 16);
}
__device__ __forceinline__ float bf2f(unsigned short u) {
    union { unsigned u; float f; } x; x.u = ((unsigned)u) << 16;
    return x.f;
}

// ---------------- Kernel 1: W[k,i] = sum_f pw[f] * filters[f,k,i]  (bf16 out)
__global__ __launch_bounds__(256) void wb_build(const float* __restrict__ filters,
                                                const float* __restrict__ proj_w,
                                                unsigned short* __restrict__ Wb) {
    int gid = blockIdx.x * 256 + threadIdx.x;      // = k*256 + i
    float acc = 0.f;
#pragma unroll
    for (int f = 0; f < F_DIM; ++f)
        acc += proj_w[f] * filters[f * (COUT * CIN) + gid];
    Wb[gid] = f2bf(acc);
}

// ---------------- Kernel 2: x'[m, n] = nf[m,:] @ W[n,:]^T + bias  (bf16 out)
// M = B*N_DIM = 16384, K = 256, N = 256.  LDS-free: 256 blocks x 4 waves,
// block = 64 rows, wave owns 64 cols. Frags loaded straight from global (L2).
__global__ __launch_bounds__(256) void xp_gemm(const float* __restrict__ nf,
                                               const unsigned short* __restrict__ Wb,
                                               const float* __restrict__ proj_b,
                                               unsigned short* __restrict__ xp) {
    const int tid  = threadIdx.x;
    const int lane = tid & 63;
    const int wv   = tid >> 6;        // 0..3
    const int m0   = blockIdx.x * 64;
    const int lrow = lane & 15;
    const int kgrp = lane >> 4;       // 0..3
    const float bias = proj_b[0];

    f32x4 acc[4][4];
#pragma unroll
    for (int a = 0; a < 4; ++a)
#pragma unroll
        for (int b = 0; b < 4; ++b)
            acc[a][b] = (f32x4){0.f, 0.f, 0.f, 0.f};

#pragma unroll
    for (int ks = 0; ks < 8; ++ks) {              // K = 8 * 32
        const int klane = ks * 32 + kgrp * 8;
        short8 af[4], bfr[4];
#pragma unroll
        for (int fm = 0; fm < 4; ++fm) {
            const float* ap = nf + (size_t)(m0 + fm * 16 + lrow) * CIN + klane;
            float4 a0 = *(const float4*)ap;
            float4 a1 = *(const float4*)(ap + 4);
            short8 t;
            t[0] = (short)f2bf(a0.x); t[1] = (short)f2bf(a0.y);
            t[2] = (short)f2bf(a0.z); t[3] = (short)f2bf(a0.w);
            t[4] = (short)f2bf(a1.x); t[5] = (short)f2bf(a1.y);
            t[6] = (short)f2bf(a1.z); t[7] = (short)f2bf(a1.w);
            af[fm] = t;
        }
#pragma unroll
        for (int fn = 0; fn < 4; ++fn) {
            const unsigned short* bp =
                Wb + (size_t)(wv * 64 + fn * 16 + lrow) * CIN + klane;
            bfr[fn] = *(const short8*)bp;         // 16B aligned
        }
#pragma unroll
        for (int fm = 0; fm < 4; ++fm)
#pragma unroll
            for (int fn = 0; fn < 4; ++fn)
                acc[fm][fn] = __builtin_amdgcn_mfma_f32_16x16x32_bf16(
                    af[fm], bfr[fn], acc[fm][fn], 0, 0, 0);
    }

    // C/D layout: col = lane&15, row = (lane>>4)*4 + r
#pragma unroll
    for (int fm = 0; fm < 4; ++fm) {
#pragma unroll
        for (int fn = 0; fn < 4; ++fn) {
            const int gcol = wv * 64 + fn * 16 + lrow;
#pragma unroll
            for (int r = 0; r < 4; ++r) {
                const int grow = m0 + fm * 16 + kgrp * 4 + r;
                xp[(size_t)grow * COUT + gcol] = f2bf(acc[fm][fn][r] + bias);
            }
        }
    }
}

// ---------------- Kernel 3: sparse row aggregation.
// One block per output row (b,i). XCD swizzle: b = bid&7 so each XCD's L2
// holds exactly one batch's x' (1 MB bf16).
__global__ __launch_bounds__(256) void agg_sparse(const float* __restrict__ adj,
                                                  const unsigned short* __restrict__ xp,
                                                  float* __restrict__ out) {
    __shared__ int   s_idx[N_DIM];
    __shared__ float s_val[N_DIM];
    __shared__ int   s_wcnt[4];
    __shared__ float s_wdeg[4];

    const int tid  = threadIdx.x;
    const int lane = tid & 63;
    const int wid  = tid >> 6;
    const int bid  = blockIdx.x;
    const int b    = bid & 7;         // XCD-locality: batch == XCD
    const int i    = bid >> 3;

    const float* row = adj + ((size_t)b * N_DIM + i) * N_DIM;

    // scan 8 consecutive entries per thread (2x float4)
    const float4* r4 = (const float4*)(row + tid * 8);
    float4 va = r4[0], vb = r4[1];
    float v[8] = {va.x, va.y, va.z, va.w, vb.x, vb.y, vb.z, vb.w};

    int   c = 0;
    float dsum = 0.f;
#pragma unroll
    for (int e = 0; e < 8; ++e) { dsum += v[e]; c += (v[e] != 0.f); }

    // deterministic compaction: wave inclusive scan of per-thread counts
    int pre = c;
#pragma unroll
    for (int off = 1; off < 64; off <<= 1) {
        int n = __shfl_up(pre, off, 64);
        if (lane >= off) pre += n;
    }
    float ds = dsum;
#pragma unroll
    for (int off = 32; off; off >>= 1) ds += __shfl_down(ds, off, 64);
    if (lane == 63) s_wcnt[wid] = pre;
    if (lane == 0)  s_wdeg[wid] = ds;
    __syncthreads();

    int base = 0;
#pragma unroll
    for (int ww = 0; ww < 4; ++ww) if (ww < wid) base += s_wcnt[ww];
    const int   cnt = s_wcnt[0] + s_wcnt[1] + s_wcnt[2] + s_wcnt[3];
    const float deg = s_wdeg[0] + s_wdeg[1] + s_wdeg[2] + s_wdeg[3];

    int p = base + (pre - c);
#pragma unroll
    for (int e = 0; e < 8; ++e) {
        if (v[e] != 0.f) { s_idx[p] = tid * 8 + e; s_val[p] = v[e]; ++p; }
    }
    __syncthreads();

    // gather-accumulate: thread owns column k = tid
    const unsigned short* xb = xp + (size_t)b * N_DIM * COUT + tid;
    float acc = 0.f;
    int t = 0;
    for (; t + 4 <= cnt; t += 4) {
        int j0 = s_idx[t], j1 = s_idx[t + 1], j2 = s_idx[t + 2], j3 = s_idx[t + 3];
        float w0 = s_val[t], w1 = s_val[t + 1], w2 = s_val[t + 2], w3 = s_val[t + 3];
        float x0 = bf2f(xb[(size_t)j0 * COUT]);
        float x1 = bf2f(xb[(size_t)j1 * COUT]);
        float x2 = bf2f(xb[(size_t)j2 * COUT]);
        float x3 = bf2f(xb[(size_t)j3 * COUT]);
        acc += w0 * x0; acc += w1 * x1; acc += w2 * x2; acc += w3 * x3;
    }
    for (; t < cnt; ++t)
        acc += s_val[t] * bf2f(xb[(size_t)s_idx[t] * COUT]);

    out[((size_t)b * N_DIM + i) * COUT + tid] = acc / (deg + EPS);
}

extern "C" void kernel_launch(void* const* d_in, const int* in_sizes, int n_in,
                              void* d_out, int out_size, void* d_ws, size_t ws_size,
                              hipStream_t stream) {
    const float* nf      = (const float*)d_in[0];
    const float* adj     = (const float*)d_in[1];
    const float* filters = (const float*)d_in[2];
    const float* proj_w  = (const float*)d_in[3];
    const float* proj_b  = (const float*)d_in[4];
    float* out = (float*)d_out;

    unsigned short* Wb = (unsigned short*)d_ws;                          // 128 KB
    unsigned short* xp = (unsigned short*)((char*)d_ws + COUT * CIN * 2); // 8 MB

    wb_build<<<(COUT * CIN) / 256, 256, 0, stream>>>(filters, proj_w, Wb);
    xp_gemm<<<(B_DIM * N_DIM) / 64, 256, 0, stream>>>(nf, Wb, proj_b, xp);
    agg_sparse<<<B_DIM * N_DIM, 256, 0, stream>>>(adj, xp, out);
}

// Round 4
// 59.747 us; speedup vs baseline: 1.2382x; 1.2382x over previous
//
#include <hip/hip_runtime.h>
#include <hip/hip_bf16.h>

#define B_DIM  8
#define N_DIM  2048
#define CIN    256
#define COUT   256
#define F_DIM  8
#define EPS    1e-4f

using short8 = __attribute__((ext_vector_type(8))) short;
using f32x4  = __attribute__((ext_vector_type(4))) float;

__device__ __forceinline__ unsigned short f2bf(float f) {
    union { float f; unsigned u; } x; x.f = f;
    unsigned r = x.u + 0x7FFFu + ((x.u >> 16) & 1u);   // RNE
    return (unsigned short)(r >> 16);
}
__device__ __forceinline__ float uf(unsigned u) {
    union { unsigned u; float f; } x; x.u = u;
    return x.f;
}

// ---------------- Kernel 1: W[k,i] = sum_f pw[f] * filters[f,k,i]  (bf16 out)
__global__ __launch_bounds__(256) void wb_build(const float* __restrict__ filters,
                                                const float* __restrict__ proj_w,
                                                unsigned short* __restrict__ Wb) {
    int gid = blockIdx.x * 256 + threadIdx.x;      // = k*256 + i
    float acc = 0.f;
#pragma unroll
    for (int f = 0; f < F_DIM; ++f)
        acc += proj_w[f] * filters[f * (COUT * CIN) + gid];
    Wb[gid] = f2bf(acc);
}

// ---------------- Kernel 2: x'[m, n] = nf[m,:] @ W[n,:]^T + bias  (bf16 out)
__global__ __launch_bounds__(256) void xp_gemm(const float* __restrict__ nf,
                                               const unsigned short* __restrict__ Wb,
                                               const float* __restrict__ proj_b,
                                               unsigned short* __restrict__ xp) {
    const int tid  = threadIdx.x;
    const int lane = tid & 63;
    const int wv   = tid >> 6;        // 0..3
    const int m0   = blockIdx.x * 64;
    const int lrow = lane & 15;
    const int kgrp = lane >> 4;       // 0..3
    const float bias = proj_b[0];

    f32x4 acc[4][4];
#pragma unroll
    for (int a = 0; a < 4; ++a)
#pragma unroll
        for (int b = 0; b < 4; ++b)
            acc[a][b] = (f32x4){0.f, 0.f, 0.f, 0.f};

#pragma unroll
    for (int ks = 0; ks < 8; ++ks) {              // K = 8 * 32
        const int klane = ks * 32 + kgrp * 8;
        short8 af[4], bfr[4];
#pragma unroll
        for (int fm = 0; fm < 4; ++fm) {
            const float* ap = nf + (size_t)(m0 + fm * 16 + lrow) * CIN + klane;
            float4 a0 = *(const float4*)ap;
            float4 a1 = *(const float4*)(ap + 4);
            short8 t;
            t[0] = (short)f2bf(a0.x); t[1] = (short)f2bf(a0.y);
            t[2] = (short)f2bf(a0.z); t[3] = (short)f2bf(a0.w);
            t[4] = (short)f2bf(a1.x); t[5] = (short)f2bf(a1.y);
            t[6] = (short)f2bf(a1.z); t[7] = (short)f2bf(a1.w);
            af[fm] = t;
        }
#pragma unroll
        for (int fn = 0; fn < 4; ++fn) {
            const unsigned short* bp =
                Wb + (size_t)(wv * 64 + fn * 16 + lrow) * CIN + klane;
            bfr[fn] = *(const short8*)bp;         // 16B aligned
        }
#pragma unroll
        for (int fm = 0; fm < 4; ++fm)
#pragma unroll
            for (int fn = 0; fn < 4; ++fn)
                acc[fm][fn] = __builtin_amdgcn_mfma_f32_16x16x32_bf16(
                    af[fm], bfr[fn], acc[fm][fn], 0, 0, 0);
    }

    // C/D layout: col = lane&15, row = (lane>>4)*4 + r
#pragma unroll
    for (int fm = 0; fm < 4; ++fm) {
#pragma unroll
        for (int fn = 0; fn < 4; ++fn) {
            const int gcol = wv * 64 + fn * 16 + lrow;
#pragma unroll
            for (int r = 0; r < 4; ++r) {
                const int grow = m0 + fm * 16 + kgrp * 4 + r;
                xp[(size_t)grow * COUT + gcol] = f2bf(acc[fm][fn][r] + bias);
            }
        }
    }
}

// ---------------- Kernel 3: sparse row aggregation, wave-per-row.
// Block = 4 waves = 4 rows of batch b = bid&7 (XCD-local xp).
// Lane owns 4 channels; per neighbor: one coalesced uint2 (4 bf16) load.
// adj values are exactly {0,1}: deg = popcount, unweighted sum.
__global__ __launch_bounds__(256) void agg_sparse(const float* __restrict__ adj,
                                                  const unsigned short* __restrict__ xp,
                                                  float* __restrict__ out) {
    __shared__ unsigned short s_idx[4][N_DIM];

    const int tid  = threadIdx.x;
    const int lane = tid & 63;
    const int wid  = tid >> 6;
    const int bid  = blockIdx.x;
    const int b    = bid & 7;                 // batch == XCD
    const int i    = (bid >> 3) * 4 + wid;    // row in batch

    // ---- scan row: 8 coalesced float4 loads; lane's elems: j = q*256 + lane*4 + e
    const float* row = adj + ((size_t)b * N_DIM + i) * N_DIM;
    float4 v[8];
#pragma unroll
    for (int q = 0; q < 8; ++q)
        v[q] = *(const float4*)(row + q * 256 + lane * 4);

    unsigned nz = 0u;
#pragma unroll
    for (int q = 0; q < 8; ++q) {
        nz |= (v[q].x != 0.f ? 1u : 0u) << (4 * q + 0);
        nz |= (v[q].y != 0.f ? 1u : 0u) << (4 * q + 1);
        nz |= (v[q].z != 0.f ? 1u : 0u) << (4 * q + 2);
        nz |= (v[q].w != 0.f ? 1u : 0u) << (4 * q + 3);
    }
    const int c = __popc(nz);

    // wave-inclusive scan of counts
    int pre = c;
#pragma unroll
    for (int off = 1; off < 64; off <<= 1) {
        int n = __shfl_up(pre, off, 64);
        if (lane >= off) pre += n;
    }
    const int total = __shfl(pre, 63, 64);    // == degree (values are exactly 1.0)

    // compact indices (fixed, deterministic order)
    int p = pre - c;
    unsigned m = nz;
    while (m) {
        int e = __builtin_ctz(m);
        m &= m - 1;
        s_idx[wid][p++] = (unsigned short)(((e >> 2) << 8) + (lane << 2) + (e & 3));
    }
    __syncthreads();   // order ds_writes before cross-lane ds_reads

    // ---- gather: lane accumulates its 4 channels over all neighbors
    const unsigned short* xb = xp + (size_t)b * (N_DIM * COUT) + lane * 4;
    float a0 = 0.f, a1 = 0.f, a2 = 0.f, a3 = 0.f;
    int t = 0;
    for (; t + 4 <= total; t += 4) {
        ushort4 jj = *(const ushort4*)&s_idx[wid][t];
        uint2 u0 = *(const uint2*)(xb + (int)jj.x * COUT);
        uint2 u1 = *(const uint2*)(xb + (int)jj.y * COUT);
        uint2 u2 = *(const uint2*)(xb + (int)jj.z * COUT);
        uint2 u3 = *(const uint2*)(xb + (int)jj.w * COUT);
        a0 += uf(u0.x << 16); a1 += uf(u0.x & 0xFFFF0000u);
        a2 += uf(u0.y << 16); a3 += uf(u0.y & 0xFFFF0000u);
        a0 += uf(u1.x << 16); a1 += uf(u1.x & 0xFFFF0000u);
        a2 += uf(u1.y << 16); a3 += uf(u1.y & 0xFFFF0000u);
        a0 += uf(u2.x << 16); a1 += uf(u2.x & 0xFFFF0000u);
        a2 += uf(u2.y << 16); a3 += uf(u2.y & 0xFFFF0000u);
        a0 += uf(u3.x << 16); a1 += uf(u3.x & 0xFFFF0000u);
        a2 += uf(u3.y << 16); a3 += uf(u3.y & 0xFFFF0000u);
    }
    for (; t < total; ++t) {
        int j = s_idx[wid][t];
        uint2 u = *(const uint2*)(xb + j * COUT);
        a0 += uf(u.x << 16); a1 += uf(u.x & 0xFFFF0000u);
        a2 += uf(u.y << 16); a3 += uf(u.y & 0xFFFF0000u);
    }

    const float inv = __builtin_amdgcn_rcpf((float)total + EPS);
    float4 o = {a0 * inv, a1 * inv, a2 * inv, a3 * inv};
    *(float4*)(out + ((size_t)b * N_DIM + i) * COUT + lane * 4) = o;
}

extern "C" void kernel_launch(void* const* d_in, const int* in_sizes, int n_in,
                              void* d_out, int out_size, void* d_ws, size_t ws_size,
                              hipStream_t stream) {
    const float* nf      = (const float*)d_in[0];
    const float* adj     = (const float*)d_in[1];
    const float* filters = (const float*)d_in[2];
    const float* proj_w  = (const float*)d_in[3];
    const float* proj_b  = (const float*)d_in[4];
    float* out = (float*)d_out;

    unsigned short* Wb = (unsigned short*)d_ws;                           // 128 KB
    unsigned short* xp = (unsigned short*)((char*)d_ws + COUT * CIN * 2); // 8 MB

    wb_build<<<(COUT * CIN) / 256, 256, 0, stream>>>(filters, proj_w, Wb);
    xp_gemm<<<(B_DIM * N_DIM) / 64, 256, 0, stream>>>(nf, Wb, proj_b, xp);
    agg_sparse<<<(B_DIM * N_DIM) / 4, 256, 0, stream>>>(adj, xp, out);
}

// Round 5
// 59.721 us; speedup vs baseline: 1.2387x; 1.0004x over previous
//
#include <hip/hip_runtime.h>
#include <hip/hip_bf16.h>

#define B_DIM  8
#define N_DIM  2048
#define CIN    256
#define COUT   256
#define F_DIM  8
#define EPS    1e-4f

using short8   = __attribute__((ext_vector_type(8))) short;
using ushort8v = __attribute__((ext_vector_type(8))) unsigned short;
using f32x4    = __attribute__((ext_vector_type(4))) float;

__device__ __forceinline__ unsigned short f2bf(float f) {
    union { float f; unsigned u; } x; x.f = f;
    unsigned r = x.u + 0x7FFFu + ((x.u >> 16) & 1u);   // RNE
    return (unsigned short)(r >> 16);
}
__device__ __forceinline__ float uf(unsigned u) {
    union { unsigned u; float f; } x; x.u = u;
    return x.f;
}

// ---------------- Kernel 1: W[k,i] = sum_f pw[f] * filters[f,k,i]  (bf16 out)
__global__ __launch_bounds__(256) void wb_build(const float* __restrict__ filters,
                                                const float* __restrict__ proj_w,
                                                unsigned short* __restrict__ Wb) {
    int gid = blockIdx.x * 256 + threadIdx.x;      // = k*256 + i
    float acc = 0.f;
#pragma unroll
    for (int f = 0; f < F_DIM; ++f)
        acc += proj_w[f] * filters[f * (COUT * CIN) + gid];
    Wb[gid] = f2bf(acc);
}

// ---------------- Kernel 2: x'[m, n] = nf[m,:] @ W[n,:]^T + bias  (bf16 out)
__global__ __launch_bounds__(256) void xp_gemm(const float* __restrict__ nf,
                                               const unsigned short* __restrict__ Wb,
                                               const float* __restrict__ proj_b,
                                               unsigned short* __restrict__ xp) {
    const int tid  = threadIdx.x;
    const int lane = tid & 63;
    const int wv   = tid >> 6;        // 0..3
    const int m0   = blockIdx.x * 64;
    const int lrow = lane & 15;
    const int kgrp = lane >> 4;       // 0..3
    const float bias = proj_b[0];

    f32x4 acc[4][4];
#pragma unroll
    for (int a = 0; a < 4; ++a)
#pragma unroll
        for (int b = 0; b < 4; ++b)
            acc[a][b] = (f32x4){0.f, 0.f, 0.f, 0.f};

#pragma unroll
    for (int ks = 0; ks < 8; ++ks) {              // K = 8 * 32
        const int klane = ks * 32 + kgrp * 8;
        short8 af[4], bfr[4];
#pragma unroll
        for (int fm = 0; fm < 4; ++fm) {
            const float* ap = nf + (size_t)(m0 + fm * 16 + lrow) * CIN + klane;
            float4 a0 = *(const float4*)ap;
            float4 a1 = *(const float4*)(ap + 4);
            short8 t;
            t[0] = (short)f2bf(a0.x); t[1] = (short)f2bf(a0.y);
            t[2] = (short)f2bf(a0.z); t[3] = (short)f2bf(a0.w);
            t[4] = (short)f2bf(a1.x); t[5] = (short)f2bf(a1.y);
            t[6] = (short)f2bf(a1.z); t[7] = (short)f2bf(a1.w);
            af[fm] = t;
        }
#pragma unroll
        for (int fn = 0; fn < 4; ++fn) {
            const unsigned short* bp =
                Wb + (size_t)(wv * 64 + fn * 16 + lrow) * CIN + klane;
            bfr[fn] = *(const short8*)bp;         // 16B aligned
        }
#pragma unroll
        for (int fm = 0; fm < 4; ++fm)
#pragma unroll
            for (int fn = 0; fn < 4; ++fn)
                acc[fm][fn] = __builtin_amdgcn_mfma_f32_16x16x32_bf16(
                    af[fm], bfr[fn], acc[fm][fn], 0, 0, 0);
    }

    // C/D layout: col = lane&15, row = (lane>>4)*4 + r
#pragma unroll
    for (int fm = 0; fm < 4; ++fm) {
#pragma unroll
        for (int fn = 0; fn < 4; ++fn) {
            const int gcol = wv * 64 + fn * 16 + lrow;
#pragma unroll
            for (int r = 0; r < 4; ++r) {
                const int grow = m0 + fm * 16 + kgrp * 4 + r;
                xp[(size_t)grow * COUT + gcol] = f2bf(acc[fm][fn][r] + bias);
            }
        }
    }
}

// ---------------- Kernel 3: sparse row aggregation, wave-per-row.
// Block = 4 waves = 4 rows of batch b = bid&7 (XCD-local xp).
// Lane owns 4 channels; per neighbor one coalesced uint2 (4 bf16) load.
// adj in {0,1}: deg = popcount, unweighted sum. Wave-synchronous LDS
// (each wave reads only its own s_idx[wid]) -> no __syncthreads.
__global__ __launch_bounds__(256) void agg_sparse(const float* __restrict__ adj,
                                                  const unsigned short* __restrict__ xp,
                                                  float* __restrict__ out) {
    __shared__ unsigned short s_idx[4][N_DIM];

    const int tid  = threadIdx.x;
    const int lane = tid & 63;
    const int wid  = tid >> 6;
    const int bid  = blockIdx.x;
    const int b    = bid & 7;                 // batch == XCD
    const int i    = (bid >> 3) * 4 + wid;    // row in batch

    // ---- scan row: 8 coalesced float4 loads; lane's elems: j = q*256 + lane*4 + e
    const float* row = adj + ((size_t)b * N_DIM + i) * N_DIM;
    float4 v[8];
#pragma unroll
    for (int q = 0; q < 8; ++q)
        v[q] = *(const float4*)(row + q * 256 + lane * 4);

    unsigned nz = 0u;
#pragma unroll
    for (int q = 0; q < 8; ++q) {
        nz |= (v[q].x != 0.f ? 1u : 0u) << (4 * q + 0);
        nz |= (v[q].y != 0.f ? 1u : 0u) << (4 * q + 1);
        nz |= (v[q].z != 0.f ? 1u : 0u) << (4 * q + 2);
        nz |= (v[q].w != 0.f ? 1u : 0u) << (4 * q + 3);
    }
    const int c = __popc(nz);

    // wave-inclusive scan of counts
    int pre = c;
#pragma unroll
    for (int off = 1; off < 64; off <<= 1) {
        int n = __shfl_up(pre, off, 64);
        if (lane >= off) pre += n;
    }
    const int total = __shfl(pre, 63, 64);    // == degree (values are exactly 1.0)

    // compact indices (fixed, deterministic order)
    int p = pre - c;
    unsigned m = nz;
    while (m) {
        int e = __builtin_ctz(m);
        m &= m - 1;
        s_idx[wid][p++] = (unsigned short)(((e >> 2) << 8) + (lane << 2) + (e & 3));
    }
    // no __syncthreads: wave-private LDS region, DS ops in-order per wave

    // ---- gather: lane accumulates its 4 channels; 8 loads in flight
    const unsigned short* xb = xp + (size_t)b * (N_DIM * COUT) + lane * 4;
    float a0 = 0.f, a1 = 0.f, a2 = 0.f, a3 = 0.f;
    float c0 = 0.f, c1 = 0.f, c2 = 0.f, c3 = 0.f;
    int t = 0;
    for (; t + 8 <= total; t += 8) {
        ushort8v jj = *(const ushort8v*)&s_idx[wid][t];
        uint2 u0 = *(const uint2*)(xb + (int)jj[0] * COUT);
        uint2 u1 = *(const uint2*)(xb + (int)jj[1] * COUT);
        uint2 u2 = *(const uint2*)(xb + (int)jj[2] * COUT);
        uint2 u3 = *(const uint2*)(xb + (int)jj[3] * COUT);
        uint2 u4 = *(const uint2*)(xb + (int)jj[4] * COUT);
        uint2 u5 = *(const uint2*)(xb + (int)jj[5] * COUT);
        uint2 u6 = *(const uint2*)(xb + (int)jj[6] * COUT);
        uint2 u7 = *(const uint2*)(xb + (int)jj[7] * COUT);
        a0 += uf(u0.x << 16); a1 += uf(u0.x & 0xFFFF0000u);
        a2 += uf(u0.y << 16); a3 += uf(u0.y & 0xFFFF0000u);
        c0 += uf(u1.x << 16); c1 += uf(u1.x & 0xFFFF0000u);
        c2 += uf(u1.y << 16); c3 += uf(u1.y & 0xFFFF0000u);
        a0 += uf(u2.x << 16); a1 += uf(u2.x & 0xFFFF0000u);
        a2 += uf(u2.y << 16); a3 += uf(u2.y & 0xFFFF0000u);
        c0 += uf(u3.x << 16); c1 += uf(u3.x & 0xFFFF0000u);
        c2 += uf(u3.y << 16); c3 += uf(u3.y & 0xFFFF0000u);
        a0 += uf(u4.x << 16); a1 += uf(u4.x & 0xFFFF0000u);
        a2 += uf(u4.y << 16); a3 += uf(u4.y & 0xFFFF0000u);
        c0 += uf(u5.x << 16); c1 += uf(u5.x & 0xFFFF0000u);
        c2 += uf(u5.y << 16); c3 += uf(u5.y & 0xFFFF0000u);
        a0 += uf(u6.x << 16); a1 += uf(u6.x & 0xFFFF0000u);
        a2 += uf(u6.y << 16); a3 += uf(u6.y & 0xFFFF0000u);
        c0 += uf(u7.x << 16); c1 += uf(u7.x & 0xFFFF0000u);
        c2 += uf(u7.y << 16); c3 += uf(u7.y & 0xFFFF0000u);
    }
    for (; t < total; ++t) {
        int j = s_idx[wid][t];
        uint2 u = *(const uint2*)(xb + j * COUT);
        a0 += uf(u.x << 16); a1 += uf(u.x & 0xFFFF0000u);
        a2 += uf(u.y << 16); a3 += uf(u.y & 0xFFFF0000u);
    }
    a0 += c0; a1 += c1; a2 += c2; a3 += c3;

    const float inv = __builtin_amdgcn_rcpf((float)total + EPS);
    float4 o = {a0 * inv, a1 * inv, a2 * inv, a3 * inv};
    *(float4*)(out + ((size_t)b * N_DIM + i) * COUT + lane * 4) = o;
}

extern "C" void kernel_launch(void* const* d_in, const int* in_sizes, int n_in,
                              void* d_out, int out_size, void* d_ws, size_t ws_size,
                              hipStream_t stream) {
    const float* nf      = (const float*)d_in[0];
    const float* adj     = (const float*)d_in[1];
    const float* filters = (const float*)d_in[2];
    const float* proj_w  = (const float*)d_in[3];
    const float* proj_b  = (const float*)d_in[4];
    float* out = (float*)d_out;

    unsigned short* Wb = (unsigned short*)d_ws;                           // 128 KB
    unsigned short* xp = (unsigned short*)((char*)d_ws + COUT * CIN * 2); // 8 MB

    wb_build<<<(COUT * CIN) / 256, 256, 0, stream>>>(filters, proj_w, Wb);
    xp_gemm<<<(B_DIM * N_DIM) / 64, 256, 0, stream>>>(nf, Wb, proj_b, xp);
    agg_sparse<<<(B_DIM * N_DIM) / 4, 256, 0, stream>>>(adj, xp, out);
}